// Round 3
// baseline (306.319 us; speedup 1.0000x reference)
//
#include <hip/hip_runtime.h>

// MultiHeadAttention fused: B=2, T=2048, D=1024, H=16, DH=64.
// Inputs fp32 (per reference), output fp32. Internally bf16 MFMA, fp32 accum.
// Pipeline: [cvt x] + [transpose W] -> [QKV gemm] -> [flash attn] -> [out gemm + bias]

typedef unsigned short u16;
typedef __attribute__((ext_vector_type(8))) short short8;  // 8 x bf16 (4 VGPRs)
typedef __attribute__((ext_vector_type(4))) float f32x4;   // MFMA C/D frag

#define B_ 2
#define T_ 2048
#define D_ 1024
#define H_ 16
#define DH_ 64
#define M_ (B_ * T_)            // 4096 rows of x
#define SCALE_LOG2E 0.18033688011112042f  // (1/sqrt(64)) * log2(e)
#define NEG_BIG -3.0e4f         // mask sentinel: exp2f(NEG_BIG - m) == 0

__device__ __forceinline__ u16 f2bf(float f) {
  union { float f; unsigned u; } v; v.f = f;
  unsigned r = v.u + 0x7fffu + ((v.u >> 16) & 1u);  // RNE
  return (u16)(r >> 16);
}

// ---------------------------------------------------------------------------
// Kernel 0: convert x fp32 -> bf16. 4M elements, 8/thread.
// ---------------------------------------------------------------------------
__global__ __launch_bounds__(256) void cvt_x(const float* __restrict__ x,
                                             u16* __restrict__ xb) {
  const int i = (blockIdx.x * 256 + threadIdx.x) * 8;
  float4 a = *(const float4*)(x + i);
  float4 b = *(const float4*)(x + i + 4);
  short8 o;
  o[0] = (short)f2bf(a.x); o[1] = (short)f2bf(a.y);
  o[2] = (short)f2bf(a.z); o[3] = (short)f2bf(a.w);
  o[4] = (short)f2bf(b.x); o[5] = (short)f2bf(b.y);
  o[6] = (short)f2bf(b.z); o[7] = (short)f2bf(b.w);
  *(short8*)(xb + i) = o;
}

// ---------------------------------------------------------------------------
// Kernel 1: transpose + convert the 4 weight matrices fp32 [K][N] -> bf16 [N][K]
// grid (16,16,4), block 256. 64x64 tiles through LDS (+8 pad).
// ---------------------------------------------------------------------------
__global__ __launch_bounds__(256) void transpose_w(
    const float* __restrict__ w0, const float* __restrict__ w1,
    const float* __restrict__ w2, const float* __restrict__ w3,
    u16* __restrict__ outT) {
  __shared__ u16 Tl[64][72];
  const int z = blockIdx.z;
  const float* src = (z == 0) ? w0 : (z == 1) ? w1 : (z == 2) ? w2 : w3;
  const int r0 = blockIdx.y * 64, c0 = blockIdx.x * 64;
  const int tid = threadIdx.x;
  const int rr = tid >> 2, cc = (tid & 3) * 16;

  const float* p = src + (size_t)(r0 + rr) * D_ + c0 + cc;
  float4 f0 = *(const float4*)p;
  float4 f1 = *(const float4*)(p + 4);
  float4 f2 = *(const float4*)(p + 8);
  float4 f3 = *(const float4*)(p + 12);
  Tl[rr][cc + 0] = f2bf(f0.x); Tl[rr][cc + 1] = f2bf(f0.y);
  Tl[rr][cc + 2] = f2bf(f0.z); Tl[rr][cc + 3] = f2bf(f0.w);
  Tl[rr][cc + 4] = f2bf(f1.x); Tl[rr][cc + 5] = f2bf(f1.y);
  Tl[rr][cc + 6] = f2bf(f1.z); Tl[rr][cc + 7] = f2bf(f1.w);
  Tl[rr][cc + 8] = f2bf(f2.x); Tl[rr][cc + 9] = f2bf(f2.y);
  Tl[rr][cc +10] = f2bf(f2.z); Tl[rr][cc +11] = f2bf(f2.w);
  Tl[rr][cc +12] = f2bf(f3.x); Tl[rr][cc +13] = f2bf(f3.y);
  Tl[rr][cc +14] = f2bf(f3.z); Tl[rr][cc +15] = f2bf(f3.w);
  __syncthreads();

  u16* o = outT + (size_t)z * D_ * D_ + (size_t)(c0 + rr) * D_ + r0 + cc;
  short8 x0, x1;
#pragma unroll
  for (int i = 0; i < 8; i++) x0[i] = (short)Tl[cc + i][rr];
#pragma unroll
  for (int i = 0; i < 8; i++) x1[i] = (short)Tl[cc + 8 + i][rr];
  *(short8*)o = x0;
  *(short8*)(o + 8) = x1;
}

// ---------------------------------------------------------------------------
// Kernel 2: QKV projection. C[m][n] = sum_k x[m][k] * WT[n][k]. (bf16 in/out)
// 128x128 C-tile, 4 waves in 2x2, each wave 4x4 MFMA tiles (16x16x32 bf16).
// Output remapped to [B,H,T,DH]. grid (8, 32, 3), block 256.
// ---------------------------------------------------------------------------
__global__ __launch_bounds__(256) void qkv_gemm(
    const u16* __restrict__ x, const u16* __restrict__ wT,
    u16* __restrict__ qkv) {
  __shared__ u16 As[128][40];  // +8 pad keeps 16B align (80B rows)
  __shared__ u16 Bs[128][40];

  const int z = blockIdx.z;
  const u16* W = wT + (size_t)z * D_ * D_;
  u16* out = qkv + (size_t)z * M_ * D_;
  const int n0 = blockIdx.x * 128;
  const int m0 = blockIdx.y * 128;
  const int tid = threadIdx.x;
  const int lane = tid & 63, w = tid >> 6;
  const int quad = lane >> 4, l16 = lane & 15;
  const int wr = w >> 1, wc = w & 1;

  f32x4 acc[4][4] = {};
  const int srow = tid >> 1;         // 0..127
  const int scol = (tid & 1) * 16;   // 0 or 16

  for (int k0 = 0; k0 < D_; k0 += 32) {
    const u16* ap = x + (size_t)(m0 + srow) * D_ + k0 + scol;
    short8 a0 = *(const short8*)ap;
    short8 a1 = *(const short8*)(ap + 8);
    const u16* bp = W + (size_t)(n0 + srow) * D_ + k0 + scol;
    short8 b0 = *(const short8*)bp;
    short8 b1 = *(const short8*)(bp + 8);
    *(short8*)&As[srow][scol] = a0;
    *(short8*)&As[srow][scol + 8] = a1;
    *(short8*)&Bs[srow][scol] = b0;
    *(short8*)&Bs[srow][scol + 8] = b1;
    __syncthreads();

    short8 af[4], bf[4];
#pragma unroll
    for (int i = 0; i < 4; i++)
      af[i] = *(const short8*)&As[wr * 64 + i * 16 + l16][quad * 8];
#pragma unroll
    for (int i = 0; i < 4; i++)
      bf[i] = *(const short8*)&Bs[wc * 64 + i * 16 + l16][quad * 8];
#pragma unroll
    for (int i = 0; i < 4; i++)
#pragma unroll
      for (int j = 0; j < 4; j++)
        acc[i][j] = __builtin_amdgcn_mfma_f32_16x16x32_bf16(af[i], bf[j], acc[i][j], 0, 0, 0);
    __syncthreads();
  }

  // epilogue: C/D layout col=l16, row=quad*4+r.  m -> (b,t), n -> (h,dh)
#pragma unroll
  for (int i = 0; i < 4; i++) {
#pragma unroll
    for (int j = 0; j < 4; j++) {
      const int n = n0 + wc * 64 + j * 16 + l16;
      const int h = n >> 6, dh = n & 63;
#pragma unroll
      for (int r = 0; r < 4; r++) {
        const int m = m0 + wr * 64 + i * 16 + quad * 4 + r;
        const int b = m >> 11, t = m & (T_ - 1);
        out[(((size_t)(b * H_ + h)) * T_ + t) * DH_ + dh] = f2bf(acc[i][j][r]);
      }
    }
  }
}

// ---------------------------------------------------------------------------
// Kernel 3: causal flash attention. grid (T/64=32, B*H=32), block 256.
// Each wave owns a 16-q-row MFMA block; workgroup stages 64-kv K/V tiles.
// ---------------------------------------------------------------------------
__global__ __launch_bounds__(256) void attn(
    const u16* __restrict__ qg, const u16* __restrict__ kg,
    const u16* __restrict__ vg, u16* __restrict__ ctx) {
  __shared__ u16 Ks[64][72];       // [kv][dh], +8 pad
  __shared__ u16 Vs[64][72];       // transposed: [dh][kv], +8 pad
  __shared__ u16 Ps[4][16][72];    // per-wave P round-trip (C-layout -> A-layout)

  const int qt = blockIdx.x;       // q tile (64 rows)
  const int bh = blockIdx.y;       // b*H + h
  const int tid = threadIdx.x;
  const int w = tid >> 6, lane = tid & 63;
  const int quad = lane >> 4, l16 = lane & 15;
  const int q0 = qt * 64;
  const size_t base = (size_t)bh * T_ * DH_;

  // Q fragments for this wave (rows q0 + w*16 .. +15), k = dh
  const int qrow = q0 + w * 16 + l16;
  short8 qf0 = *(const short8*)(qg + base + (size_t)qrow * DH_ + quad * 8);
  short8 qf1 = *(const short8*)(qg + base + (size_t)qrow * DH_ + 32 + quad * 8);

  f32x4 oacc[4] = {};
  float mi[4], li[4];
#pragma unroll
  for (int r = 0; r < 4; r++) { mi[r] = NEG_BIG; li[r] = 0.f; }

  const int srow = tid >> 2;          // 0..63
  const int scol = (tid & 3) * 16;
  const int kvend = q0 + 64;

  for (int kv0 = 0; kv0 < kvend; kv0 += 64) {
    // stage K [kv][dh]
    const u16* kp = kg + base + (size_t)(kv0 + srow) * DH_ + scol;
    short8 k0v = *(const short8*)kp;
    short8 k1v = *(const short8*)(kp + 8);
    *(short8*)&Ks[srow][scol] = k0v;
    *(short8*)&Ks[srow][scol + 8] = k1v;
    // stage V transposed -> Vs[dh][kv]
    const u16* vp = vg + base + (size_t)(kv0 + srow) * DH_ + scol;
    short8 v0v = *(const short8*)vp;
    short8 v1v = *(const short8*)(vp + 8);
#pragma unroll
    for (int i = 0; i < 8; i++) Vs[scol + i][srow] = (u16)v0v[i];
#pragma unroll
    for (int i = 0; i < 8; i++) Vs[scol + 8 + i][srow] = (u16)v1v[i];
    __syncthreads();

    // S = Q K^T (scaled, masked) : 4 col-blocks of 16 kv
    float s[4][4];
#pragma unroll
    for (int cb = 0; cb < 4; cb++) {
      f32x4 sv = {};
      short8 kf0 = *(const short8*)&Ks[cb * 16 + l16][quad * 8];
      short8 kf1 = *(const short8*)&Ks[cb * 16 + l16][32 + quad * 8];
      sv = __builtin_amdgcn_mfma_f32_16x16x32_bf16(qf0, kf0, sv, 0, 0, 0);
      sv = __builtin_amdgcn_mfma_f32_16x16x32_bf16(qf1, kf1, sv, 0, 0, 0);
      const int col = kv0 + cb * 16 + l16;
#pragma unroll
      for (int r = 0; r < 4; r++) {
        const int row = q0 + w * 16 + quad * 4 + r;
        s[cb][r] = (col <= row) ? sv[r] * SCALE_LOG2E : NEG_BIG;
      }
    }

    // online softmax (base-2 domain), row reduction across 16 lanes of a quad
    float p[4][4];
#pragma unroll
    for (int r = 0; r < 4; r++) {
      float t = fmaxf(fmaxf(s[0][r], s[1][r]), fmaxf(s[2][r], s[3][r]));
#pragma unroll
      for (int off = 1; off < 16; off <<= 1) t = fmaxf(t, __shfl_xor(t, off, 64));
      const float mnew = fmaxf(mi[r], t);
      const float alpha = exp2f(mi[r] - mnew);
      mi[r] = mnew;
      float rs = 0.f;
#pragma unroll
      for (int cb = 0; cb < 4; cb++) { p[cb][r] = exp2f(s[cb][r] - mnew); rs += p[cb][r]; }
#pragma unroll
      for (int off = 1; off < 16; off <<= 1) rs += __shfl_xor(rs, off, 64);
      li[r] = li[r] * alpha + rs;
#pragma unroll
      for (int cb = 0; cb < 4; cb++) oacc[cb][r] *= alpha;
    }

    // P: C-layout -> A-layout via per-wave LDS (barrier: data crosses lanes)
#pragma unroll
    for (int cb = 0; cb < 4; cb++)
#pragma unroll
      for (int r = 0; r < 4; r++)
        Ps[w][quad * 4 + r][cb * 16 + l16] = f2bf(p[cb][r]);
    __syncthreads();

    short8 pa0 = *(const short8*)&Ps[w][l16][quad * 8];
    short8 pa1 = *(const short8*)&Ps[w][l16][32 + quad * 8];
#pragma unroll
    for (int cb = 0; cb < 4; cb++) {
      short8 vf0 = *(const short8*)&Vs[cb * 16 + l16][quad * 8];
      short8 vf1 = *(const short8*)&Vs[cb * 16 + l16][32 + quad * 8];
      oacc[cb] = __builtin_amdgcn_mfma_f32_16x16x32_bf16(pa0, vf0, oacc[cb], 0, 0, 0);
      oacc[cb] = __builtin_amdgcn_mfma_f32_16x16x32_bf16(pa1, vf1, oacc[cb], 0, 0, 0);
    }
    __syncthreads();
  }

  // epilogue: ctx[b][t][h*64+dh] = oacc / l
  const int b = bh >> 4, h = bh & 15;
#pragma unroll
  for (int cb = 0; cb < 4; cb++) {
#pragma unroll
    for (int r = 0; r < 4; r++) {
      const int trow = q0 + w * 16 + quad * 4 + r;
      const int col = h * 64 + cb * 16 + l16;
      ctx[((size_t)(b * T_ + trow)) * D_ + col] = f2bf(oacc[cb][r] / li[r]);
    }
  }
}

// ---------------------------------------------------------------------------
// Kernel 4: output projection + bias. out[m][n] = ctx @ WoT^T + bo. (fp32 out)
// grid (8, 32), block 256.
// ---------------------------------------------------------------------------
__global__ __launch_bounds__(256) void out_gemm(
    const u16* __restrict__ ctx, const u16* __restrict__ woT,
    const float* __restrict__ bo, float* __restrict__ out) {
  __shared__ u16 As[128][40];
  __shared__ u16 Bs[128][40];

  const int n0 = blockIdx.x * 128;
  const int m0 = blockIdx.y * 128;
  const int tid = threadIdx.x;
  const int lane = tid & 63, w = tid >> 6;
  const int quad = lane >> 4, l16 = lane & 15;
  const int wr = w >> 1, wc = w & 1;

  f32x4 acc[4][4] = {};
  const int srow = tid >> 1;
  const int scol = (tid & 1) * 16;

  for (int k0 = 0; k0 < D_; k0 += 32) {
    const u16* ap = ctx + (size_t)(m0 + srow) * D_ + k0 + scol;
    short8 a0 = *(const short8*)ap;
    short8 a1 = *(const short8*)(ap + 8);
    const u16* bp = woT + (size_t)(n0 + srow) * D_ + k0 + scol;
    short8 b0 = *(const short8*)bp;
    short8 b1 = *(const short8*)(bp + 8);
    *(short8*)&As[srow][scol] = a0;
    *(short8*)&As[srow][scol + 8] = a1;
    *(short8*)&Bs[srow][scol] = b0;
    *(short8*)&Bs[srow][scol + 8] = b1;
    __syncthreads();

    short8 af[4], bf[4];
#pragma unroll
    for (int i = 0; i < 4; i++)
      af[i] = *(const short8*)&As[wr * 64 + i * 16 + l16][quad * 8];
#pragma unroll
    for (int i = 0; i < 4; i++)
      bf[i] = *(const short8*)&Bs[wc * 64 + i * 16 + l16][quad * 8];
#pragma unroll
    for (int i = 0; i < 4; i++)
#pragma unroll
      for (int j = 0; j < 4; j++)
        acc[i][j] = __builtin_amdgcn_mfma_f32_16x16x32_bf16(af[i], bf[j], acc[i][j], 0, 0, 0);
    __syncthreads();
  }

#pragma unroll
  for (int i = 0; i < 4; i++) {
#pragma unroll
    for (int j = 0; j < 4; j++) {
      const int n = n0 + wc * 64 + j * 16 + l16;
      const float bias = bo[n];
#pragma unroll
      for (int r = 0; r < 4; r++) {
        const int m = m0 + wr * 64 + i * 16 + quad * 4 + r;
        out[(size_t)m * D_ + n] = acc[i][j][r] + bias;
      }
    }
  }
}

// ---------------------------------------------------------------------------
extern "C" void kernel_launch(void* const* d_in, const int* in_sizes, int n_in,
                              void* d_out, int out_size, void* d_ws, size_t ws_size,
                              hipStream_t stream) {
  const float* x  = (const float*)d_in[0];
  const float* Wq = (const float*)d_in[1];
  const float* Wk = (const float*)d_in[2];
  const float* Wv = (const float*)d_in[3];
  const float* Wo = (const float*)d_in[4];
  const float* bo = (const float*)d_in[5];
  float* out = (float*)d_out;

  // workspace carve (u16 elements): xb[4M] | wT[4M] | qkv[12M] | ctx[4M] = 48MB
  u16* ws  = (u16*)d_ws;
  u16* xb  = ws;                                  // 4096*1024
  u16* wT  = xb + (size_t)M_ * D_;                // 4 * 1024*1024
  u16* qkv = wT + (size_t)4 * D_ * D_;            // 3 * 4096*1024
  u16* ctx = qkv + (size_t)3 * M_ * D_;           // 4096*1024

  cvt_x<<<dim3(M_ * D_ / (256 * 8)), 256, 0, stream>>>(x, xb);
  transpose_w<<<dim3(16, 16, 4), 256, 0, stream>>>(Wq, Wk, Wv, Wo, wT);
  qkv_gemm<<<dim3(D_ / 128, M_ / 128, 3), 256, 0, stream>>>(xb, wT, qkv);
  attn<<<dim3(T_ / 64, B_ * H_), 256, 0, stream>>>(
      qkv, qkv + (size_t)M_ * D_, qkv + (size_t)2 * M_ * D_, ctx);
  out_gemm<<<dim3(D_ / 128, M_ / 128), 256, 0, stream>>>(ctx, wT + (size_t)3 * D_ * D_, bo, out);
}

// Round 4
// 276.373 us; speedup vs baseline: 1.1084x; 1.1084x over previous
//
#include <hip/hip_runtime.h>

// MultiHeadAttention fused: B=2, T=2048, D=1024, H=16, DH=64.
// Inputs fp32 (per reference), output fp32. Internally bf16 MFMA, fp32 accum.
// Pipeline: [cvt x] + [transpose W] -> [QKV gemm (V transposed)] -> [flash attn S^T] -> [out gemm + bias]

typedef unsigned short u16;
typedef __attribute__((ext_vector_type(8))) short short8;  // 8 x bf16 (4 VGPRs)
typedef __attribute__((ext_vector_type(4))) float f32x4;   // MFMA C/D frag

#define B_ 2
#define T_ 2048
#define D_ 1024
#define H_ 16
#define DH_ 64
#define M_ (B_ * T_)            // 4096 rows of x
#define SCALE_LOG2E 0.18033688011112042f  // (1/sqrt(64)) * log2(e)
#define NEG_BIG -3.0e4f         // mask sentinel: exp2f(NEG_BIG - m) == 0

__device__ __forceinline__ u16 f2bf(float f) {
  union { float f; unsigned u; } v; v.f = f;
  unsigned r = v.u + 0x7fffu + ((v.u >> 16) & 1u);  // RNE
  return (u16)(r >> 16);
}

// ---------------------------------------------------------------------------
// Kernel 0: convert x fp32 -> bf16. 4M elements, 8/thread.
// ---------------------------------------------------------------------------
__global__ __launch_bounds__(256) void cvt_x(const float* __restrict__ x,
                                             u16* __restrict__ xb) {
  const int i = (blockIdx.x * 256 + threadIdx.x) * 8;
  float4 a = *(const float4*)(x + i);
  float4 b = *(const float4*)(x + i + 4);
  short8 o;
  o[0] = (short)f2bf(a.x); o[1] = (short)f2bf(a.y);
  o[2] = (short)f2bf(a.z); o[3] = (short)f2bf(a.w);
  o[4] = (short)f2bf(b.x); o[5] = (short)f2bf(b.y);
  o[6] = (short)f2bf(b.z); o[7] = (short)f2bf(b.w);
  *(short8*)(xb + i) = o;
}

// ---------------------------------------------------------------------------
// Kernel 1: transpose + convert the 4 weight matrices fp32 [K][N] -> bf16 [N][K]
// grid (16,16,4), block 256. 64x64 tiles through LDS (+8 pad).
// ---------------------------------------------------------------------------
__global__ __launch_bounds__(256) void transpose_w(
    const float* __restrict__ w0, const float* __restrict__ w1,
    const float* __restrict__ w2, const float* __restrict__ w3,
    u16* __restrict__ outT) {
  __shared__ u16 Tl[64][72];
  const int z = blockIdx.z;
  const float* src = (z == 0) ? w0 : (z == 1) ? w1 : (z == 2) ? w2 : w3;
  const int r0 = blockIdx.y * 64, c0 = blockIdx.x * 64;
  const int tid = threadIdx.x;
  const int rr = tid >> 2, cc = (tid & 3) * 16;

  const float* p = src + (size_t)(r0 + rr) * D_ + c0 + cc;
  float4 f0 = *(const float4*)p;
  float4 f1 = *(const float4*)(p + 4);
  float4 f2 = *(const float4*)(p + 8);
  float4 f3 = *(const float4*)(p + 12);
  Tl[rr][cc + 0] = f2bf(f0.x); Tl[rr][cc + 1] = f2bf(f0.y);
  Tl[rr][cc + 2] = f2bf(f0.z); Tl[rr][cc + 3] = f2bf(f0.w);
  Tl[rr][cc + 4] = f2bf(f1.x); Tl[rr][cc + 5] = f2bf(f1.y);
  Tl[rr][cc + 6] = f2bf(f1.z); Tl[rr][cc + 7] = f2bf(f1.w);
  Tl[rr][cc + 8] = f2bf(f2.x); Tl[rr][cc + 9] = f2bf(f2.y);
  Tl[rr][cc +10] = f2bf(f2.z); Tl[rr][cc +11] = f2bf(f2.w);
  Tl[rr][cc +12] = f2bf(f3.x); Tl[rr][cc +13] = f2bf(f3.y);
  Tl[rr][cc +14] = f2bf(f3.z); Tl[rr][cc +15] = f2bf(f3.w);
  __syncthreads();

  u16* o = outT + (size_t)z * D_ * D_ + (size_t)(c0 + rr) * D_ + r0 + cc;
  short8 x0, x1;
#pragma unroll
  for (int i = 0; i < 8; i++) x0[i] = (short)Tl[cc + i][rr];
#pragma unroll
  for (int i = 0; i < 8; i++) x1[i] = (short)Tl[cc + 8 + i][rr];
  *(short8*)o = x0;
  *(short8*)(o + 8) = x1;
}

// ---------------------------------------------------------------------------
// Kernel 2: QKV projection. C[m][n] = sum_k x[m][k] * WT[n][k]. (bf16 in/out)
// 128x128 C-tile, 4 waves in 2x2, each wave 4x4 MFMA tiles (16x16x32 bf16).
// Q,K written [B,H,T,DH]; V written TRANSPOSED [B,H,DH,T] for attn staging.
// grid (8, 32, 3), block 256.
// ---------------------------------------------------------------------------
__global__ __launch_bounds__(256) void qkv_gemm(
    const u16* __restrict__ x, const u16* __restrict__ wT,
    u16* __restrict__ qkv) {
  __shared__ u16 As[128][40];  // +8 pad keeps 16B align (80B rows)
  __shared__ u16 Bs[128][40];

  const int z = blockIdx.z;
  const u16* W = wT + (size_t)z * D_ * D_;
  u16* out = qkv + (size_t)z * M_ * D_;
  const int n0 = blockIdx.x * 128;
  const int m0 = blockIdx.y * 128;
  const int tid = threadIdx.x;
  const int lane = tid & 63, w = tid >> 6;
  const int quad = lane >> 4, l16 = lane & 15;
  const int wr = w >> 1, wc = w & 1;

  f32x4 acc[4][4] = {};
  const int srow = tid >> 1;         // 0..127
  const int scol = (tid & 1) * 16;   // 0 or 16

  for (int k0 = 0; k0 < D_; k0 += 32) {
    const u16* ap = x + (size_t)(m0 + srow) * D_ + k0 + scol;
    short8 a0 = *(const short8*)ap;
    short8 a1 = *(const short8*)(ap + 8);
    const u16* bp = W + (size_t)(n0 + srow) * D_ + k0 + scol;
    short8 b0 = *(const short8*)bp;
    short8 b1 = *(const short8*)(bp + 8);
    *(short8*)&As[srow][scol] = a0;
    *(short8*)&As[srow][scol + 8] = a1;
    *(short8*)&Bs[srow][scol] = b0;
    *(short8*)&Bs[srow][scol + 8] = b1;
    __syncthreads();

    short8 af[4], bf[4];
#pragma unroll
    for (int i = 0; i < 4; i++)
      af[i] = *(const short8*)&As[wr * 64 + i * 16 + l16][quad * 8];
#pragma unroll
    for (int i = 0; i < 4; i++)
      bf[i] = *(const short8*)&Bs[wc * 64 + i * 16 + l16][quad * 8];
#pragma unroll
    for (int i = 0; i < 4; i++)
#pragma unroll
      for (int j = 0; j < 4; j++)
        acc[i][j] = __builtin_amdgcn_mfma_f32_16x16x32_bf16(af[i], bf[j], acc[i][j], 0, 0, 0);
    __syncthreads();
  }

  // epilogue: C/D layout col=l16, row=quad*4+r.  m -> (b,t), n -> (h,dh)
#pragma unroll
  for (int i = 0; i < 4; i++) {
#pragma unroll
    for (int j = 0; j < 4; j++) {
      const int n = n0 + wc * 64 + j * 16 + l16;
      const int h = n >> 6, dh = n & 63;
#pragma unroll
      for (int r = 0; r < 4; r++) {
        const int m = m0 + wr * 64 + i * 16 + quad * 4 + r;
        const int b = m >> 11, t = m & (T_ - 1);
        if (z == 2)  // V: [b,h,dh,t]
          out[(((size_t)(b * H_ + h)) * DH_ + dh) * T_ + t] = f2bf(acc[i][j][r]);
        else         // Q,K: [b,h,t,dh]
          out[(((size_t)(b * H_ + h)) * T_ + t) * DH_ + dh] = f2bf(acc[i][j][r]);
      }
    }
  }
}

// ---------------------------------------------------------------------------
// Kernel 3: causal flash attention, S^T formulation. grid (32, 32), block 256.
// S^T = K·Q^T: C-layout col = q (lane&15) -> per-lane scalar softmax state,
// row reduction = 15 VALU + 2 shuffles.  O^T = V^T·P^T via pre-transposed V.
// ---------------------------------------------------------------------------
__global__ __launch_bounds__(256) void attn(
    const u16* __restrict__ qg, const u16* __restrict__ kg,
    const u16* __restrict__ vtg, u16* __restrict__ ctx) {
  __shared__ u16 Ks[64][72];       // [kv][dh], +8 pad
  __shared__ u16 Vs[64][72];       // [dh][kv], +8 pad (staged from vT global)
  __shared__ u16 Ps[4][16][72];    // per-wave: [q][kv] (B-operand layout)

  const int qt = gridDim.x - 1 - blockIdx.x;  // long blocks dispatch first
  const int bh = blockIdx.y;
  const int tid = threadIdx.x;
  const int w = tid >> 6, lane = tid & 63;
  const int quad = lane >> 4, l16 = lane & 15;
  const int q0 = qt * 64;
  const size_t baseQK = (size_t)bh * T_ * DH_;
  const size_t baseV  = (size_t)bh * DH_ * T_;

  // Q B-operand fragments: lane row q = q0 + w*16 + l16, k = dh contiguous
  const int qrow = q0 + w * 16 + l16;
  short8 qf0 = *(const short8*)(qg + baseQK + (size_t)qrow * DH_ + quad * 8);
  short8 qf1 = *(const short8*)(qg + baseQK + (size_t)qrow * DH_ + 32 + quad * 8);

  f32x4 oacc[4] = {};   // O^T: row dh = cb*16+quad*4+r, col q = l16
  float mi = NEG_BIG, li = 0.f;

  const int srow = tid >> 2;          // 0..63
  const int scol = (tid & 3) * 16;    // 0,16,32,48
  const int kvend = q0 + 64;
  const int wave_qmax = q0 + w * 16 + 15;  // last q row this wave owns

  for (int kv0 = 0; kv0 < kvend; kv0 += 64) {
    // stage K [kv][dh] and V^T [dh][kv] — both fully vectorized
    const u16* kp = kg + baseQK + (size_t)(kv0 + srow) * DH_ + scol;
    short8 k0v = *(const short8*)kp;
    short8 k1v = *(const short8*)(kp + 8);
    const u16* vp = vtg + baseV + (size_t)srow * T_ + kv0 + scol;
    short8 v0v = *(const short8*)vp;
    short8 v1v = *(const short8*)(vp + 8);
    *(short8*)&Ks[srow][scol] = k0v;
    *(short8*)&Ks[srow][scol + 8] = k1v;
    *(short8*)&Vs[srow][scol] = v0v;
    *(short8*)&Vs[srow][scol + 8] = v1v;
    __syncthreads();

    if (kv0 <= wave_qmax) {  // wave-uniform: skip fully-masked sub-tiles
      // S^T[kv][q] per cb: A = K (rows kv), B = Q (cols q)
      float s[4][4];
#pragma unroll
      for (int cb = 0; cb < 4; cb++) {
        f32x4 sv = {};
        short8 kf0 = *(const short8*)&Ks[cb * 16 + l16][quad * 8];
        short8 kf1 = *(const short8*)&Ks[cb * 16 + l16][32 + quad * 8];
        sv = __builtin_amdgcn_mfma_f32_16x16x32_bf16(kf0, qf0, sv, 0, 0, 0);
        sv = __builtin_amdgcn_mfma_f32_16x16x32_bf16(kf1, qf1, sv, 0, 0, 0);
#pragma unroll
        for (int r = 0; r < 4; r++) {
          const int kv = kv0 + cb * 16 + quad * 4 + r;
          s[cb][r] = (kv <= qrow) ? sv[r] * SCALE_LOG2E : NEG_BIG;
        }
      }

      // per-lane online softmax (q = qrow for ALL 16 values of this lane)
      float mloc = NEG_BIG;
#pragma unroll
      for (int cb = 0; cb < 4; cb++)
#pragma unroll
        for (int r = 0; r < 4; r++) mloc = fmaxf(mloc, s[cb][r]);
      mloc = fmaxf(mloc, __shfl_xor(mloc, 16, 64));
      mloc = fmaxf(mloc, __shfl_xor(mloc, 32, 64));
      const float mnew = fmaxf(mi, mloc);
      const float alpha = exp2f(mi - mnew);
      mi = mnew;
      float rs = 0.f;
      float p[4][4];
#pragma unroll
      for (int cb = 0; cb < 4; cb++)
#pragma unroll
        for (int r = 0; r < 4; r++) { p[cb][r] = exp2f(s[cb][r] - mnew); rs += p[cb][r]; }
      rs += __shfl_xor(rs, 16, 64);
      rs += __shfl_xor(rs, 32, 64);
      li = li * alpha + rs;
#pragma unroll
      for (int cb = 0; cb < 4; cb++)
#pragma unroll
        for (int r = 0; r < 4; r++) oacc[cb][r] *= alpha;

      // P^T(C-layout) -> P(B-operand layout) via wave-private LDS.
      // Same-wave DS ops complete in order: no workgroup barrier needed.
#pragma unroll
      for (int cb = 0; cb < 4; cb++)
#pragma unroll
        for (int r = 0; r < 4; r++)
          Ps[w][l16][cb * 16 + quad * 4 + r] = f2bf(p[cb][r]);

      short8 pa0 = *(const short8*)&Ps[w][l16][quad * 8];
      short8 pa1 = *(const short8*)&Ps[w][l16][32 + quad * 8];
#pragma unroll
      for (int cb = 0; cb < 4; cb++) {
        short8 vf0 = *(const short8*)&Vs[cb * 16 + l16][quad * 8];
        short8 vf1 = *(const short8*)&Vs[cb * 16 + l16][32 + quad * 8];
        oacc[cb] = __builtin_amdgcn_mfma_f32_16x16x32_bf16(vf0, pa0, oacc[cb], 0, 0, 0);
        oacc[cb] = __builtin_amdgcn_mfma_f32_16x16x32_bf16(vf1, pa1, oacc[cb], 0, 0, 0);
      }
    }
    __syncthreads();
  }

  // epilogue: ctx[b][t][h*64+dh] = O^T[dh][q] / li   (li >= 1: diagonal kept)
  const int b = bh >> 4, h = bh & 15;
  const float inv = 1.0f / li;
#pragma unroll
  for (int cb = 0; cb < 4; cb++) {
#pragma unroll
    for (int r = 0; r < 4; r++) {
      const int dh = cb * 16 + quad * 4 + r;
      ctx[((size_t)(b * T_ + qrow)) * D_ + h * 64 + dh] = f2bf(oacc[cb][r] * inv);
    }
  }
}

// ---------------------------------------------------------------------------
// Kernel 4: output projection + bias. out[m][n] = ctx @ WoT^T + bo. (fp32 out)
// grid (8, 32), block 256.
// ---------------------------------------------------------------------------
__global__ __launch_bounds__(256) void out_gemm(
    const u16* __restrict__ ctx, const u16* __restrict__ woT,
    const float* __restrict__ bo, float* __restrict__ out) {
  __shared__ u16 As[128][40];
  __shared__ u16 Bs[128][40];

  const int n0 = blockIdx.x * 128;
  const int m0 = blockIdx.y * 128;
  const int tid = threadIdx.x;
  const int lane = tid & 63, w = tid >> 6;
  const int quad = lane >> 4, l16 = lane & 15;
  const int wr = w >> 1, wc = w & 1;

  f32x4 acc[4][4] = {};
  const int srow = tid >> 1;
  const int scol = (tid & 1) * 16;

  for (int k0 = 0; k0 < D_; k0 += 32) {
    const u16* ap = ctx + (size_t)(m0 + srow) * D_ + k0 + scol;
    short8 a0 = *(const short8*)ap;
    short8 a1 = *(const short8*)(ap + 8);
    const u16* bp = woT + (size_t)(n0 + srow) * D_ + k0 + scol;
    short8 b0 = *(const short8*)bp;
    short8 b1 = *(const short8*)(bp + 8);
    *(short8*)&As[srow][scol] = a0;
    *(short8*)&As[srow][scol + 8] = a1;
    *(short8*)&Bs[srow][scol] = b0;
    *(short8*)&Bs[srow][scol + 8] = b1;
    __syncthreads();

    short8 af[4], bf[4];
#pragma unroll
    for (int i = 0; i < 4; i++)
      af[i] = *(const short8*)&As[wr * 64 + i * 16 + l16][quad * 8];
#pragma unroll
    for (int i = 0; i < 4; i++)
      bf[i] = *(const short8*)&Bs[wc * 64 + i * 16 + l16][quad * 8];
#pragma unroll
    for (int i = 0; i < 4; i++)
#pragma unroll
      for (int j = 0; j < 4; j++)
        acc[i][j] = __builtin_amdgcn_mfma_f32_16x16x32_bf16(af[i], bf[j], acc[i][j], 0, 0, 0);
    __syncthreads();
  }

#pragma unroll
  for (int i = 0; i < 4; i++) {
#pragma unroll
    for (int j = 0; j < 4; j++) {
      const int n = n0 + wc * 64 + j * 16 + l16;
      const float bias = bo[n];
#pragma unroll
      for (int r = 0; r < 4; r++) {
        const int m = m0 + wr * 64 + i * 16 + quad * 4 + r;
        out[(size_t)m * D_ + n] = acc[i][j][r] + bias;
      }
    }
  }
}

// ---------------------------------------------------------------------------
extern "C" void kernel_launch(void* const* d_in, const int* in_sizes, int n_in,
                              void* d_out, int out_size, void* d_ws, size_t ws_size,
                              hipStream_t stream) {
  const float* x  = (const float*)d_in[0];
  const float* Wq = (const float*)d_in[1];
  const float* Wk = (const float*)d_in[2];
  const float* Wv = (const float*)d_in[3];
  const float* Wo = (const float*)d_in[4];
  const float* bo = (const float*)d_in[5];
  float* out = (float*)d_out;

  // workspace carve (u16 elements): xb[4M] | wT[4M] | qkv[12M] | ctx[4M] = 48MB
  u16* ws  = (u16*)d_ws;
  u16* xb  = ws;                                  // 4096*1024
  u16* wT  = xb + (size_t)M_ * D_;                // 4 * 1024*1024
  u16* qkv = wT + (size_t)4 * D_ * D_;            // 3 * 4096*1024
  u16* ctx = qkv + (size_t)3 * M_ * D_;           // 4096*1024

  cvt_x<<<dim3(M_ * D_ / (256 * 8)), 256, 0, stream>>>(x, xb);
  transpose_w<<<dim3(16, 16, 4), 256, 0, stream>>>(Wq, Wk, Wv, Wo, wT);
  qkv_gemm<<<dim3(D_ / 128, M_ / 128, 3), 256, 0, stream>>>(xb, wT, qkv);
  attn<<<dim3(T_ / 64, B_ * H_), 256, 0, stream>>>(
      qkv, qkv + (size_t)M_ * D_, qkv + (size_t)2 * M_ * D_, ctx);
  out_gemm<<<dim3(D_ / 128, M_ / 128), 256, 0, stream>>>(ctx, wT + (size_t)3 * D_ * D_, bo, out);
}

// Round 5
// 240.001 us; speedup vs baseline: 1.2763x; 1.1515x over previous
//
#include <hip/hip_runtime.h>

// MultiHeadAttention fused: B=2, T=2048, D=1024, H=16, DH=64.
// Inputs fp32 (per reference), output fp32. Internally bf16 MFMA, fp32 accum.
// Pipeline: [cvt x] + [transpose W] -> [QKV gemm (m97 staging)] -> [transpose V]
//           -> [flash attn S^T, prefetch-pipelined] -> [out gemm + bias]

typedef unsigned short u16;
typedef __attribute__((ext_vector_type(8))) short short8;  // 8 x bf16 (4 VGPRs)
typedef __attribute__((ext_vector_type(4))) float f32x4;   // MFMA C/D frag

#define B_ 2
#define T_ 2048
#define D_ 1024
#define H_ 16
#define DH_ 64
#define M_ (B_ * T_)            // 4096 rows of x
#define SCALE_LOG2E 0.18033688011112042f  // (1/sqrt(64)) * log2(e)
#define NEG_BIG -3.0e4f         // mask sentinel: exp2f(NEG_BIG - m) == 0

// async global->LDS, 16B per lane; LDS dest = wave-uniform base + lane*16
#define GLOAD16(g, l)                                                     \
  __builtin_amdgcn_global_load_lds(                                       \
      (const __attribute__((address_space(1))) void*)(g),                 \
      (__attribute__((address_space(3))) void*)(l), 16, 0, 0)

__device__ __forceinline__ u16 f2bf(float f) {
  union { float f; unsigned u; } v; v.f = f;
  unsigned r = v.u + 0x7fffu + ((v.u >> 16) & 1u);  // RNE
  return (u16)(r >> 16);
}

// ---------------------------------------------------------------------------
// Kernel 0: convert x fp32 -> bf16. 4M elements, 8/thread.
// ---------------------------------------------------------------------------
__global__ __launch_bounds__(256) void cvt_x(const float* __restrict__ x,
                                             u16* __restrict__ xb) {
  const int i = (blockIdx.x * 256 + threadIdx.x) * 8;
  float4 a = *(const float4*)(x + i);
  float4 b = *(const float4*)(x + i + 4);
  short8 o;
  o[0] = (short)f2bf(a.x); o[1] = (short)f2bf(a.y);
  o[2] = (short)f2bf(a.z); o[3] = (short)f2bf(a.w);
  o[4] = (short)f2bf(b.x); o[5] = (short)f2bf(b.y);
  o[6] = (short)f2bf(b.z); o[7] = (short)f2bf(b.w);
  *(short8*)(xb + i) = o;
}

// ---------------------------------------------------------------------------
// Kernel 1: transpose + convert the 4 weight matrices fp32 [K][N] -> bf16 [N][K]
// grid (16,16,4), block 256. 64x64 tiles through LDS (+8 pad).
// ---------------------------------------------------------------------------
__global__ __launch_bounds__(256) void transpose_w(
    const float* __restrict__ w0, const float* __restrict__ w1,
    const float* __restrict__ w2, const float* __restrict__ w3,
    u16* __restrict__ outT) {
  __shared__ u16 Tl[64][72];
  const int z = blockIdx.z;
  const float* src = (z == 0) ? w0 : (z == 1) ? w1 : (z == 2) ? w2 : w3;
  const int r0 = blockIdx.y * 64, c0 = blockIdx.x * 64;
  const int tid = threadIdx.x;
  const int rr = tid >> 2, cc = (tid & 3) * 16;

  const float* p = src + (size_t)(r0 + rr) * D_ + c0 + cc;
  float4 f0 = *(const float4*)p;
  float4 f1 = *(const float4*)(p + 4);
  float4 f2 = *(const float4*)(p + 8);
  float4 f3 = *(const float4*)(p + 12);
  Tl[rr][cc + 0] = f2bf(f0.x); Tl[rr][cc + 1] = f2bf(f0.y);
  Tl[rr][cc + 2] = f2bf(f0.z); Tl[rr][cc + 3] = f2bf(f0.w);
  Tl[rr][cc + 4] = f2bf(f1.x); Tl[rr][cc + 5] = f2bf(f1.y);
  Tl[rr][cc + 6] = f2bf(f1.z); Tl[rr][cc + 7] = f2bf(f1.w);
  Tl[rr][cc + 8] = f2bf(f2.x); Tl[rr][cc + 9] = f2bf(f2.y);
  Tl[rr][cc +10] = f2bf(f2.z); Tl[rr][cc +11] = f2bf(f2.w);
  Tl[rr][cc +12] = f2bf(f3.x); Tl[rr][cc +13] = f2bf(f3.y);
  Tl[rr][cc +14] = f2bf(f3.z); Tl[rr][cc +15] = f2bf(f3.w);
  __syncthreads();

  u16* o = outT + (size_t)z * D_ * D_ + (size_t)(c0 + rr) * D_ + r0 + cc;
  short8 x0, x1;
#pragma unroll
  for (int i = 0; i < 8; i++) x0[i] = (short)Tl[cc + i][rr];
#pragma unroll
  for (int i = 0; i < 8; i++) x1[i] = (short)Tl[cc + 8 + i][rr];
  *(short8*)o = x0;
  *(short8*)(o + 8) = x1;
}

// ---------------------------------------------------------------------------
// Kernel 2: QKV projection. C[m][n] = sum_k x[m][k] * WT[n][k]. (bf16 in/out)
// m97-style: global_load_lds width-16 staging into unpadded [128][32] LDS.
// All outputs [B,H,T,DH] (V transposed by a separate kernel).
// grid (8, 32, 3), block 256.
// ---------------------------------------------------------------------------
__global__ __launch_bounds__(256) void qkv_gemm(
    const u16* __restrict__ x, const u16* __restrict__ wT,
    u16* __restrict__ qkv) {
  __shared__ u16 As[128][32];  // unpadded: global_load_lds needs lane-order layout
  __shared__ u16 Bs[128][32];

  const int z = blockIdx.z;
  const u16* W = wT + (size_t)z * D_ * D_;
  u16* out = qkv + (size_t)z * M_ * D_;
  const int n0 = blockIdx.x * 128;
  const int m0 = blockIdx.y * 128;
  const int tid = threadIdx.x;
  const int lane = tid & 63, w = tid >> 6;
  const int quad = lane >> 4, l16 = lane & 15;
  const int wr = w >> 1, wc = w & 1;

  f32x4 acc[4][4] = {};
  // staging map: wave w, lane l -> LDS row w*16 + (l>>2) (+64 for 2nd inst),
  // col (l&3)*8; 16B per lane, contiguous in lane order from base w*1024B.
  const int grow = w * 16 + (lane >> 2);
  const int gcol = (lane & 3) * 8;
  u16* lA = (u16*)As + w * 512;   // 1024 B per wave
  u16* lB = (u16*)Bs + w * 512;

  for (int k0 = 0; k0 < D_; k0 += 32) {
    const u16* gA = x + (size_t)(m0 + grow) * D_ + k0 + gcol;
    const u16* gB = W + (size_t)(n0 + grow) * D_ + k0 + gcol;
    GLOAD16(gA, lA);
    GLOAD16(gA + (size_t)64 * D_, lA + 2048);
    GLOAD16(gB, lB);
    GLOAD16(gB + (size_t)64 * D_, lB + 2048);
    __syncthreads();

    short8 af[4], bf[4];
#pragma unroll
    for (int i = 0; i < 4; i++)
      af[i] = *(const short8*)&As[wr * 64 + i * 16 + l16][quad * 8];
#pragma unroll
    for (int i = 0; i < 4; i++)
      bf[i] = *(const short8*)&Bs[wc * 64 + i * 16 + l16][quad * 8];
#pragma unroll
    for (int i = 0; i < 4; i++)
#pragma unroll
      for (int j = 0; j < 4; j++)
        acc[i][j] = __builtin_amdgcn_mfma_f32_16x16x32_bf16(af[i], bf[j], acc[i][j], 0, 0, 0);
    __syncthreads();
  }

  // epilogue: C/D layout col=l16, row=quad*4+r.  m -> (b,t), n -> (h,dh)
#pragma unroll
  for (int i = 0; i < 4; i++) {
#pragma unroll
    for (int j = 0; j < 4; j++) {
      const int n = n0 + wc * 64 + j * 16 + l16;
      const int h = n >> 6, dh = n & 63;
#pragma unroll
      for (int r = 0; r < 4; r++) {
        const int m = m0 + wr * 64 + i * 16 + quad * 4 + r;
        const int b = m >> 11, t = m & (T_ - 1);
        out[(((size_t)(b * H_ + h)) * T_ + t) * DH_ + dh] = f2bf(acc[i][j][r]);
      }
    }
  }
}

// ---------------------------------------------------------------------------
// Kernel 2b: transpose V [bh][t][dh] -> V^T [bh][dh][t]. grid (32, 32), block 256.
// ---------------------------------------------------------------------------
__global__ __launch_bounds__(256) void transpose_v(
    const u16* __restrict__ v, u16* __restrict__ vT) {
  __shared__ u16 Tl[64][72];
  const int t0 = blockIdx.x * 64;
  const int bh = blockIdx.y;
  const int tid = threadIdx.x;
  const int rr = tid >> 2, cc = (tid & 3) * 16;

  const u16* p = v + (size_t)bh * T_ * DH_ + (size_t)(t0 + rr) * DH_ + cc;
  short8 a0 = *(const short8*)p;
  short8 a1 = *(const short8*)(p + 8);
  *(short8*)&Tl[rr][cc] = a0;
  *(short8*)&Tl[rr][cc + 8] = a1;
  __syncthreads();

  // out[dh=rr][t = t0+cc+i] = Tl[cc+i][rr]
  u16* o = vT + (size_t)bh * DH_ * T_ + (size_t)rr * T_ + t0 + cc;
  short8 x0, x1;
#pragma unroll
  for (int i = 0; i < 8; i++) x0[i] = (short)Tl[cc + i][rr];
#pragma unroll
  for (int i = 0; i < 8; i++) x1[i] = (short)Tl[cc + 8 + i][rr];
  *(short8*)o = x0;
  *(short8*)(o + 8) = x1;
}

// ---------------------------------------------------------------------------
// Kernel 3: causal flash attention, S^T formulation, prefetch-pipelined.
// grid (32, 32), block 256. Next K/V tile's global loads issue before the
// compute barrier, completing under the current tile's compute.
// ---------------------------------------------------------------------------
__global__ __launch_bounds__(256) void attn(
    const u16* __restrict__ qg, const u16* __restrict__ kg,
    const u16* __restrict__ vtg, u16* __restrict__ ctx) {
  __shared__ u16 Ks[64][72];       // [kv][dh], +8 pad
  __shared__ u16 Vs[64][72];       // [dh][kv], +8 pad (from vT global)
  __shared__ u16 Ps[4][16][72];    // per-wave: [q][kv] (B-operand layout)

  const int qt = gridDim.x - 1 - blockIdx.x;  // long blocks dispatch first
  const int bh = blockIdx.y;
  const int tid = threadIdx.x;
  const int w = tid >> 6, lane = tid & 63;
  const int quad = lane >> 4, l16 = lane & 15;
  const int q0 = qt * 64;
  const size_t baseQK = (size_t)bh * T_ * DH_;
  const size_t baseV  = (size_t)bh * DH_ * T_;

  // Q B-operand fragments: lane row q = q0 + w*16 + l16, k = dh contiguous
  const int qrow = q0 + w * 16 + l16;
  short8 qf0 = *(const short8*)(qg + baseQK + (size_t)qrow * DH_ + quad * 8);
  short8 qf1 = *(const short8*)(qg + baseQK + (size_t)qrow * DH_ + 32 + quad * 8);

  f32x4 oacc[4] = {};   // O^T: row dh = cb*16+quad*4+r, col q = l16
  float mi = NEG_BIG, li = 0.f;

  const int srow = tid >> 2;          // 0..63
  const int scol = (tid & 3) * 16;    // 0,16,32,48
  const int kvend = q0 + 64;
  const int wave_qmax = q0 + w * 16 + 15;

  // prefetch tile 0 into registers
  const u16* kp = kg + baseQK + (size_t)srow * DH_ + scol;
  const u16* vp = vtg + baseV + (size_t)srow * T_ + scol;
  short8 k0v = *(const short8*)kp;
  short8 k1v = *(const short8*)(kp + 8);
  short8 v0v = *(const short8*)vp;
  short8 v1v = *(const short8*)(vp + 8);

  for (int kv0 = 0; kv0 < kvend; kv0 += 64) {
    __syncthreads();                 // LDS free (prev compute done)
    *(short8*)&Ks[srow][scol] = k0v;
    *(short8*)&Ks[srow][scol + 8] = k1v;
    *(short8*)&Vs[srow][scol] = v0v;
    *(short8*)&Vs[srow][scol + 8] = v1v;
    if (kv0 + 64 < kvend) {          // issue next tile's loads now; they land
      const u16* kn = kg + baseQK + (size_t)(kv0 + 64 + srow) * DH_ + scol;
      const u16* vn = vtg + baseV + (size_t)srow * T_ + kv0 + 64 + scol;
      k0v = *(const short8*)kn;      // during this tile's compute
      k1v = *(const short8*)(kn + 8);
      v0v = *(const short8*)vn;
      v1v = *(const short8*)(vn + 8);
    }
    __syncthreads();                 // LDS ready

    if (kv0 <= wave_qmax) {          // wave-uniform: skip fully-masked tiles
      // S^T[kv][q] per cb: A = K (rows kv), B = Q (cols q)
      float s[4][4];
#pragma unroll
      for (int cb = 0; cb < 4; cb++) {
        f32x4 sv = {};
        short8 kf0 = *(const short8*)&Ks[cb * 16 + l16][quad * 8];
        short8 kf1 = *(const short8*)&Ks[cb * 16 + l16][32 + quad * 8];
        sv = __builtin_amdgcn_mfma_f32_16x16x32_bf16(kf0, qf0, sv, 0, 0, 0);
        sv = __builtin_amdgcn_mfma_f32_16x16x32_bf16(kf1, qf1, sv, 0, 0, 0);
#pragma unroll
        for (int r = 0; r < 4; r++) {
          const int kv = kv0 + cb * 16 + quad * 4 + r;
          s[cb][r] = (kv <= qrow) ? sv[r] * SCALE_LOG2E : NEG_BIG;
        }
      }

      // per-lane online softmax (q = qrow for all 16 values of this lane)
      float mloc = NEG_BIG;
#pragma unroll
      for (int cb = 0; cb < 4; cb++)
#pragma unroll
        for (int r = 0; r < 4; r++) mloc = fmaxf(mloc, s[cb][r]);
      mloc = fmaxf(mloc, __shfl_xor(mloc, 16, 64));
      mloc = fmaxf(mloc, __shfl_xor(mloc, 32, 64));
      const float mnew = fmaxf(mi, mloc);
      const float alpha = exp2f(mi - mnew);
      mi = mnew;
      float rs = 0.f;
      float p[4][4];
#pragma unroll
      for (int cb = 0; cb < 4; cb++)
#pragma unroll
        for (int r = 0; r < 4; r++) { p[cb][r] = exp2f(s[cb][r] - mnew); rs += p[cb][r]; }
      rs += __shfl_xor(rs, 16, 64);
      rs += __shfl_xor(rs, 32, 64);
      li = li * alpha + rs;
#pragma unroll
      for (int cb = 0; cb < 4; cb++)
#pragma unroll
        for (int r = 0; r < 4; r++) oacc[cb][r] *= alpha;

      // P^T(C-layout) -> P(B-operand layout) via wave-private LDS (in-order)
#pragma unroll
      for (int cb = 0; cb < 4; cb++)
#pragma unroll
        for (int r = 0; r < 4; r++)
          Ps[w][l16][cb * 16 + quad * 4 + r] = f2bf(p[cb][r]);

      short8 pa0 = *(const short8*)&Ps[w][l16][quad * 8];
      short8 pa1 = *(const short8*)&Ps[w][l16][32 + quad * 8];
#pragma unroll
      for (int cb = 0; cb < 4; cb++) {
        short8 vf0 = *(const short8*)&Vs[cb * 16 + l16][quad * 8];
        short8 vf1 = *(const short8*)&Vs[cb * 16 + l16][32 + quad * 8];
        oacc[cb] = __builtin_amdgcn_mfma_f32_16x16x32_bf16(vf0, pa0, oacc[cb], 0, 0, 0);
        oacc[cb] = __builtin_amdgcn_mfma_f32_16x16x32_bf16(vf1, pa1, oacc[cb], 0, 0, 0);
      }
    }
  }

  // epilogue: ctx[b][t][h*64+dh] = O^T[dh][q] / li   (li >= 1: diagonal kept)
  const int b = bh >> 4, h = bh & 15;
  const float inv = 1.0f / li;
#pragma unroll
  for (int cb = 0; cb < 4; cb++) {
#pragma unroll
    for (int r = 0; r < 4; r++) {
      const int dh = cb * 16 + quad * 4 + r;
      ctx[((size_t)(b * T_ + qrow)) * D_ + h * 64 + dh] = f2bf(oacc[cb][r] * inv);
    }
  }
}

// ---------------------------------------------------------------------------
// Kernel 4: output projection + bias (m97 staging). out = ctx @ WoT^T + bo.
// grid (8, 32), block 256. fp32 output.
// ---------------------------------------------------------------------------
__global__ __launch_bounds__(256) void out_gemm(
    const u16* __restrict__ ctx, const u16* __restrict__ woT,
    const float* __restrict__ bo, float* __restrict__ out) {
  __shared__ u16 As[128][32];
  __shared__ u16 Bs[128][32];

  const int n0 = blockIdx.x * 128;
  const int m0 = blockIdx.y * 128;
  const int tid = threadIdx.x;
  const int lane = tid & 63, w = tid >> 6;
  const int quad = lane >> 4, l16 = lane & 15;
  const int wr = w >> 1, wc = w & 1;

  f32x4 acc[4][4] = {};
  const int grow = w * 16 + (lane >> 2);
  const int gcol = (lane & 3) * 8;
  u16* lA = (u16*)As + w * 512;
  u16* lB = (u16*)Bs + w * 512;

  for (int k0 = 0; k0 < D_; k0 += 32) {
    const u16* gA = ctx + (size_t)(m0 + grow) * D_ + k0 + gcol;
    const u16* gB = woT + (size_t)(n0 + grow) * D_ + k0 + gcol;
    GLOAD16(gA, lA);
    GLOAD16(gA + (size_t)64 * D_, lA + 2048);
    GLOAD16(gB, lB);
    GLOAD16(gB + (size_t)64 * D_, lB + 2048);
    __syncthreads();

    short8 af[4], bf[4];
#pragma unroll
    for (int i = 0; i < 4; i++)
      af[i] = *(const short8*)&As[wr * 64 + i * 16 + l16][quad * 8];
#pragma unroll
    for (int i = 0; i < 4; i++)
      bf[i] = *(const short8*)&Bs[wc * 64 + i * 16 + l16][quad * 8];
#pragma unroll
    for (int i = 0; i < 4; i++)
#pragma unroll
      for (int j = 0; j < 4; j++)
        acc[i][j] = __builtin_amdgcn_mfma_f32_16x16x32_bf16(af[i], bf[j], acc[i][j], 0, 0, 0);
    __syncthreads();
  }

#pragma unroll
  for (int i = 0; i < 4; i++) {
#pragma unroll
    for (int j = 0; j < 4; j++) {
      const int n = n0 + wc * 64 + j * 16 + l16;
      const float bias = bo[n];
#pragma unroll
      for (int r = 0; r < 4; r++) {
        const int m = m0 + wr * 64 + i * 16 + quad * 4 + r;
        out[(size_t)m * D_ + n] = acc[i][j][r] + bias;
      }
    }
  }
}

// ---------------------------------------------------------------------------
extern "C" void kernel_launch(void* const* d_in, const int* in_sizes, int n_in,
                              void* d_out, int out_size, void* d_ws, size_t ws_size,
                              hipStream_t stream) {
  const float* x  = (const float*)d_in[0];
  const float* Wq = (const float*)d_in[1];
  const float* Wk = (const float*)d_in[2];
  const float* Wv = (const float*)d_in[3];
  const float* Wo = (const float*)d_in[4];
  const float* bo = (const float*)d_in[5];
  float* out = (float*)d_out;

  // workspace carve (u16 elements): xb[4M] | wT[4M] | qkv[12M] | ctx[4M] = 48MB
  // xb is dead after qkv_gemm -> reused as V^T buffer.
  u16* ws  = (u16*)d_ws;
  u16* xb  = ws;                                  // 4096*1024 (later: V^T)
  u16* wT  = xb + (size_t)M_ * D_;                // 4 * 1024*1024
  u16* qkv = wT + (size_t)4 * D_ * D_;            // 3 * 4096*1024
  u16* ctx = qkv + (size_t)3 * M_ * D_;           // 4096*1024
  u16* vT  = xb;

  cvt_x<<<dim3(M_ * D_ / (256 * 8)), 256, 0, stream>>>(x, xb);
  transpose_w<<<dim3(16, 16, 4), 256, 0, stream>>>(Wq, Wk, Wv, Wo, wT);
  qkv_gemm<<<dim3(D_ / 128, M_ / 128, 3), 256, 0, stream>>>(xb, wT, qkv);
  transpose_v<<<dim3(T_ / 64, B_ * H_), 256, 0, stream>>>(qkv + (size_t)2 * M_ * D_, vT);
  attn<<<dim3(T_ / 64, B_ * H_), 256, 0, stream>>>(
      qkv, qkv + (size_t)M_ * D_, vT, ctx);
  out_gemm<<<dim3(D_ / 128, M_ / 128), 256, 0, stream>>>(ctx, wT + (size_t)3 * D_ * D_, bo, out);
}